// Round 1
// baseline (3086.411 us; speedup 1.0000x reference)
//
#include <hip/hip_runtime.h>

#define F 128

// Y[n,128] = act(X[n,128]) @ W[128,128]; act = relu if do_relu.
// Block: 256 threads = 32 col-groups (tx, 4 cols each) x 8 row-groups (ty, 4 rows each)
// => 32 rows per block. W read from global (64KB, L2-resident, broadcast across ty).
__global__ __launch_bounds__(256) void gemm128(const float* __restrict__ X,
                                               const float* __restrict__ W,
                                               float* __restrict__ Y,
                                               int n, int do_relu) {
    const int tx = threadIdx.x & 31;   // col group: cols [4tx, 4tx+3]
    const int ty = threadIdx.x >> 5;   // row group
    const int row0 = blockIdx.x * 32 + ty * 4;
    if (row0 >= n) return;

    const float4* __restrict__ Wv = (const float4*)W;  // W[k][c]: float4 idx k*32 + tx
    float acc[4][4];
#pragma unroll
    for (int r = 0; r < 4; ++r)
#pragma unroll
        for (int c = 0; c < 4; ++c) acc[r][c] = 0.f;

    for (int k = 0; k < F; k += 4) {
        float4 xr[4];
#pragma unroll
        for (int r = 0; r < 4; ++r) {
            float4 v = *(const float4*)(X + (size_t)(row0 + r) * F + k);
            if (do_relu) {
                v.x = fmaxf(v.x, 0.f); v.y = fmaxf(v.y, 0.f);
                v.z = fmaxf(v.z, 0.f); v.w = fmaxf(v.w, 0.f);
            }
            xr[r] = v;
        }
#pragma unroll
        for (int kk = 0; kk < 4; ++kk) {
            float4 w = Wv[(size_t)(k + kk) * 32 + tx];
#pragma unroll
            for (int r = 0; r < 4; ++r) {
                const float xs = ((const float*)&xr[r])[kk];
                acc[r][0] = fmaf(xs, w.x, acc[r][0]);
                acc[r][1] = fmaf(xs, w.y, acc[r][1]);
                acc[r][2] = fmaf(xs, w.z, acc[r][2]);
                acc[r][3] = fmaf(xs, w.w, acc[r][3]);
            }
        }
    }
#pragma unroll
    for (int r = 0; r < 4; ++r) {
        float4 o = make_float4(acc[r][0], acc[r][1], acc[r][2], acc[r][3]);
        *(float4*)(Y + (size_t)(row0 + r) * F + tx * 4) = o;
    }
}

// OUT[dst] += w_e * XW[src] for each edge; 32 lanes/edge, float4 per lane.
__global__ __launch_bounds__(256) void scatter_add(const float* __restrict__ XW,
                                                   const int* __restrict__ ei,
                                                   const float* __restrict__ ew,
                                                   float* __restrict__ OUT, int E) {
    const int l = threadIdx.x & 31;
    const int e = blockIdx.x * 8 + (threadIdx.x >> 5);
    if (e >= E) return;
    const int src = ei[e];
    const int dst = ei[E + e];
    const float w = ew[e];
    float4 v = ((const float4*)(XW + (size_t)src * F))[l];
    float* drow = OUT + (size_t)dst * F + (size_t)l * 4;
    atomicAdd(drow + 0, v.x * w);
    atomicAdd(drow + 1, v.y * w);
    atomicAdd(drow + 2, v.z * w);
    atomicAdd(drow + 3, v.w * w);
}

// out[p, o] = sum_k Wlin[o,k]*Z[i][k] + Wlin[o,128+k]*Z[j][k]; one wave per pair.
__global__ __launch_bounds__(256) void pair_lin(const float* __restrict__ Z,
                                                const int* __restrict__ pos,
                                                const float* __restrict__ Wlin,
                                                float* __restrict__ out, int P) {
    __shared__ float WL[512];
    for (int i = threadIdx.x; i < 512; i += 256) WL[i] = Wlin[i];
    __syncthreads();

    const int lane = threadIdx.x & 63;
    const int p = blockIdx.x * 4 + (threadIdx.x >> 6);
    if (p >= P) return;
    const int a = pos[p];
    const int b = pos[P + p];
    float2 zi = ((const float2*)(Z + (size_t)a * F))[lane];
    float2 zj = ((const float2*)(Z + (size_t)b * F))[lane];
    const int k = lane * 2;
    float acc0 = zi.x * WL[k]       + zi.y * WL[k + 1]
               + zj.x * WL[128 + k] + zj.y * WL[128 + k + 1];
    float acc1 = zi.x * WL[256 + k] + zi.y * WL[256 + k + 1]
               + zj.x * WL[384 + k] + zj.y * WL[384 + k + 1];
#pragma unroll
    for (int off = 32; off > 0; off >>= 1) {
        acc0 += __shfl_down(acc0, off, 64);
        acc1 += __shfl_down(acc1, off, 64);
    }
    if (lane == 0) {
        out[(size_t)p * 2 + 0] = acc0;
        out[(size_t)p * 2 + 1] = acc1;
    }
}

extern "C" void kernel_launch(void* const* d_in, const int* in_sizes, int n_in,
                              void* d_out, int out_size, void* d_ws, size_t ws_size,
                              hipStream_t stream) {
    const float* x    = (const float*)d_in[0];
    const int*   ei1  = (const int*)  d_in[1];
    const int*   ei2  = (const int*)  d_in[2];
    const float* ew1  = (const float*)d_in[3];
    const float* ew2  = (const float*)d_in[4];
    const int*   pos  = (const int*)  d_in[5];
    const float* W1   = (const float*)d_in[6];
    const float* W2   = (const float*)d_in[7];
    const float* Wlin = (const float*)d_in[8];
    float* out = (float*)d_out;

    const int N  = in_sizes[0] / F;
    const int E1 = in_sizes[1] / 2;
    const int E2 = in_sizes[2] / 2;
    const int P  = in_sizes[5] / 2;

    float* A = (float*)d_ws;                 // N x 128
    float* B = A + (size_t)N * F;            // N x 128
    const size_t rowbytes = (size_t)N * F * sizeof(float);

    // xw1 = x @ W1
    gemm128<<<(N + 31) / 32, 256, 0, stream>>>(x, W1, A, N, 0);
    // h = segment_sum(xw1[src] * w1, dst)
    hipMemsetAsync(B, 0, rowbytes, stream);
    scatter_add<<<(E1 + 7) / 8, 256, 0, stream>>>(A, ei1, ew1, B, E1);
    // hw2 = relu(h) @ W2
    gemm128<<<(N + 31) / 32, 256, 0, stream>>>(B, W2, A, N, 1);
    // z = segment_sum(hw2[src] * w2, dst)
    hipMemsetAsync(B, 0, rowbytes, stream);
    scatter_add<<<(E2 + 7) / 8, 256, 0, stream>>>(A, ei2, ew2, B, E2);
    // out = [z[i], z[j]] @ Wlin^T
    pair_lin<<<(P + 3) / 4, 256, 0, stream>>>(B, pos, Wlin, out, P);
}

// Round 2
// 1144.042 us; speedup vs baseline: 2.6978x; 2.6978x over previous
//
#include <hip/hip_runtime.h>

#define F 128

// Y[n,128] = act(X[n,128]) @ W[128,128]; act = relu if do_relu.
__global__ __launch_bounds__(256) void gemm128(const float* __restrict__ X,
                                               const float* __restrict__ W,
                                               float* __restrict__ Y,
                                               int n, int do_relu) {
    const int tx = threadIdx.x & 31;   // col group: cols [4tx, 4tx+3]
    const int ty = threadIdx.x >> 5;   // row group
    const int row0 = blockIdx.x * 32 + ty * 4;
    if (row0 >= n) return;

    const float4* __restrict__ Wv = (const float4*)W;
    float acc[4][4];
#pragma unroll
    for (int r = 0; r < 4; ++r)
#pragma unroll
        for (int c = 0; c < 4; ++c) acc[r][c] = 0.f;

    for (int k = 0; k < F; k += 4) {
        float4 xr[4];
#pragma unroll
        for (int r = 0; r < 4; ++r) {
            float4 v = *(const float4*)(X + (size_t)(row0 + r) * F + k);
            if (do_relu) {
                v.x = fmaxf(v.x, 0.f); v.y = fmaxf(v.y, 0.f);
                v.z = fmaxf(v.z, 0.f); v.w = fmaxf(v.w, 0.f);
            }
            xr[r] = v;
        }
#pragma unroll
        for (int kk = 0; kk < 4; ++kk) {
            float4 w = Wv[(size_t)(k + kk) * 32 + tx];
#pragma unroll
            for (int r = 0; r < 4; ++r) {
                const float xs = ((const float*)&xr[r])[kk];
                acc[r][0] = fmaf(xs, w.x, acc[r][0]);
                acc[r][1] = fmaf(xs, w.y, acc[r][1]);
                acc[r][2] = fmaf(xs, w.z, acc[r][2]);
                acc[r][3] = fmaf(xs, w.w, acc[r][3]);
            }
        }
    }
#pragma unroll
    for (int r = 0; r < 4; ++r) {
        float4 o = make_float4(acc[r][0], acc[r][1], acc[r][2], acc[r][3]);
        *(float4*)(Y + (size_t)(row0 + r) * F + tx * 4) = o;
    }
}

// --- counting sort by destination -------------------------------------------

__global__ __launch_bounds__(256) void hist_dst(const int* __restrict__ ei,
                                                int* __restrict__ counts, int E) {
    for (int e = blockIdx.x * 256 + threadIdx.x; e < E; e += gridDim.x * 256)
        atomicAdd(&counts[ei[E + e]], 1);
}

// Single-block exclusive scan over counts[0..n) -> offs[0..n], cursor copy.
__global__ __launch_bounds__(1024) void scan_counts(const int* __restrict__ counts,
                                                    int* __restrict__ offs,
                                                    int* __restrict__ cursor, int n) {
    __shared__ int part[1024];
    const int per = (n + 1023) / 1024;
    const int start = threadIdx.x * per;
    const int end = min(start + per, n);
    int s = 0;
    for (int i = start; i < end; ++i) s += counts[i];
    part[threadIdx.x] = s;
    __syncthreads();
    for (int off = 1; off < 1024; off <<= 1) {
        int v = (threadIdx.x >= off) ? part[threadIdx.x - off] : 0;
        __syncthreads();
        part[threadIdx.x] += v;
        __syncthreads();
    }
    int run = (threadIdx.x == 0) ? 0 : part[threadIdx.x - 1];
    for (int i = start; i < end; ++i) {
        offs[i] = run; cursor[i] = run;
        run += counts[i];
    }
    if (threadIdx.x == 1023) offs[n] = run;
}

__global__ __launch_bounds__(256) void bucket_fill(const int* __restrict__ ei,
                                                   const float* __restrict__ ew,
                                                   int* __restrict__ cursor,
                                                   int* __restrict__ Ssrc,
                                                   float* __restrict__ Sw, int E) {
    const int e = blockIdx.x * 256 + threadIdx.x;
    if (e >= E) return;
    const int dst = ei[E + e];
    const int slot = atomicAdd(&cursor[dst], 1);
    Ssrc[slot] = ei[e];
    Sw[slot] = ew[e];
}

// OUT[v] = sum over incoming edges w_e * XW[src_e]; 32 lanes per node, no atomics.
__global__ __launch_bounds__(256) void gather_agg(const float* __restrict__ XW,
                                                  const int* __restrict__ offs,
                                                  const int* __restrict__ Ssrc,
                                                  const float* __restrict__ Sw,
                                                  float* __restrict__ OUT, int n) {
    const int l = threadIdx.x & 31;
    const int v = blockIdx.x * 8 + (threadIdx.x >> 5);
    if (v >= n) return;
    float4 acc = make_float4(0.f, 0.f, 0.f, 0.f);
    const int b = offs[v], e2 = offs[v + 1];
    for (int p = b; p < e2; ++p) {
        const int s = Ssrc[p];
        const float w = Sw[p];
        const float4 x = ((const float4*)(XW + (size_t)s * F))[l];
        acc.x = fmaf(w, x.x, acc.x);
        acc.y = fmaf(w, x.y, acc.y);
        acc.z = fmaf(w, x.z, acc.z);
        acc.w = fmaf(w, x.w, acc.w);
    }
    ((float4*)(OUT + (size_t)v * F))[l] = acc;
}

// out[p,:] = [Z[a], Z[b]] @ Wlin^T ; one 64-lane wave per pair.
__global__ __launch_bounds__(256) void pair_lin(const float* __restrict__ Z,
                                                const int* __restrict__ pos,
                                                const float* __restrict__ Wlin,
                                                float* __restrict__ out, int P) {
    __shared__ float WL[512];
    for (int i = threadIdx.x; i < 512; i += 256) WL[i] = Wlin[i];
    __syncthreads();

    const int lane = threadIdx.x & 63;
    const int p = blockIdx.x * 4 + (threadIdx.x >> 6);
    if (p >= P) return;
    const int a = pos[p];
    const int b = pos[P + p];
    float2 zi = ((const float2*)(Z + (size_t)a * F))[lane];
    float2 zj = ((const float2*)(Z + (size_t)b * F))[lane];
    const int k = lane * 2;
    float acc0 = zi.x * WL[k]       + zi.y * WL[k + 1]
               + zj.x * WL[128 + k] + zj.y * WL[128 + k + 1];
    float acc1 = zi.x * WL[256 + k] + zi.y * WL[256 + k + 1]
               + zj.x * WL[384 + k] + zj.y * WL[384 + k + 1];
#pragma unroll
    for (int off = 32; off > 0; off >>= 1) {
        acc0 += __shfl_down(acc0, off, 64);
        acc1 += __shfl_down(acc1, off, 64);
    }
    if (lane == 0) {
        out[(size_t)p * 2 + 0] = acc0;
        out[(size_t)p * 2 + 1] = acc1;
    }
}

extern "C" void kernel_launch(void* const* d_in, const int* in_sizes, int n_in,
                              void* d_out, int out_size, void* d_ws, size_t ws_size,
                              hipStream_t stream) {
    const float* x    = (const float*)d_in[0];
    const int*   ei1  = (const int*)  d_in[1];
    const int*   ei2  = (const int*)  d_in[2];
    const float* ew1  = (const float*)d_in[3];
    const float* ew2  = (const float*)d_in[4];
    const int*   pos  = (const int*)  d_in[5];
    const float* W1   = (const float*)d_in[6];
    const float* W2   = (const float*)d_in[7];
    const float* Wlin = (const float*)d_in[8];
    float* out = (float*)d_out;

    const int N  = in_sizes[0] / F;
    const int E1 = in_sizes[1] / 2;
    const int E2 = in_sizes[2] / 2;
    const int P  = in_sizes[5] / 2;
    const int Emax = E1 > E2 ? E1 : E2;

    // workspace layout
    float* A      = (float*)d_ws;                 // N x 128
    float* B      = A + (size_t)N * F;            // N x 128
    int*   counts = (int*)(B + (size_t)N * F);    // N
    int*   offs   = counts + N;                   // N+1
    int*   cursor = offs + N + 1;                 // N
    int*   Ssrc   = cursor + N;                   // Emax
    float* Sw     = (float*)(Ssrc + Emax);        // Emax

    // ---- layer 1: A = x @ W1 ; B = segment_sum over edges1 ----
    gemm128<<<(N + 31) / 32, 256, 0, stream>>>(x, W1, A, N, 0);

    hipMemsetAsync(counts, 0, (size_t)N * sizeof(int), stream);
    hist_dst<<<1024, 256, 0, stream>>>(ei1, counts, E1);
    scan_counts<<<1, 1024, 0, stream>>>(counts, offs, cursor, N);
    bucket_fill<<<(E1 + 255) / 256, 256, 0, stream>>>(ei1, ew1, cursor, Ssrc, Sw, E1);
    gather_agg<<<(N + 7) / 8, 256, 0, stream>>>(A, offs, Ssrc, Sw, B, N);

    // ---- layer 2: A = relu(B) @ W2 ; B = segment_sum over edges2 ----
    gemm128<<<(N + 31) / 32, 256, 0, stream>>>(B, W2, A, N, 1);

    hipMemsetAsync(counts, 0, (size_t)N * sizeof(int), stream);
    hist_dst<<<1024, 256, 0, stream>>>(ei2, counts, E2);
    scan_counts<<<1, 1024, 0, stream>>>(counts, offs, cursor, N);
    bucket_fill<<<(E2 + 255) / 256, 256, 0, stream>>>(ei2, ew2, cursor, Ssrc, Sw, E2);
    gather_agg<<<(N + 7) / 8, 256, 0, stream>>>(A, offs, Ssrc, Sw, B, N);

    // ---- head ----
    pair_lin<<<(P + 3) / 4, 256, 0, stream>>>(B, pos, Wlin, out, P);
}

// Round 3
// 711.073 us; speedup vs baseline: 4.3405x; 1.6089x over previous
//
#include <hip/hip_runtime.h>

#define F 128

// Y[n,128] = act(X[n,128]) @ W[128,128]; act = relu if do_relu.
__global__ __launch_bounds__(256) void gemm128(const float* __restrict__ X,
                                               const float* __restrict__ W,
                                               float* __restrict__ Y,
                                               int n, int do_relu) {
    const int tx = threadIdx.x & 31;   // col group: cols [4tx, 4tx+3]
    const int ty = threadIdx.x >> 5;   // row group
    const int row0 = blockIdx.x * 32 + ty * 4;
    if (row0 >= n) return;

    const float4* __restrict__ Wv = (const float4*)W;
    float acc[4][4];
#pragma unroll
    for (int r = 0; r < 4; ++r)
#pragma unroll
        for (int c = 0; c < 4; ++c) acc[r][c] = 0.f;

    for (int k = 0; k < F; k += 4) {
        float4 xr[4];
#pragma unroll
        for (int r = 0; r < 4; ++r) {
            float4 v = *(const float4*)(X + (size_t)(row0 + r) * F + k);
            if (do_relu) {
                v.x = fmaxf(v.x, 0.f); v.y = fmaxf(v.y, 0.f);
                v.z = fmaxf(v.z, 0.f); v.w = fmaxf(v.w, 0.f);
            }
            xr[r] = v;
        }
#pragma unroll
        for (int kk = 0; kk < 4; ++kk) {
            float4 w = Wv[(size_t)(k + kk) * 32 + tx];
#pragma unroll
            for (int r = 0; r < 4; ++r) {
                const float xs = ((const float*)&xr[r])[kk];
                acc[r][0] = fmaf(xs, w.x, acc[r][0]);
                acc[r][1] = fmaf(xs, w.y, acc[r][1]);
                acc[r][2] = fmaf(xs, w.z, acc[r][2]);
                acc[r][3] = fmaf(xs, w.w, acc[r][3]);
            }
        }
    }
#pragma unroll
    for (int r = 0; r < 4; ++r) {
        float4 o = make_float4(acc[r][0], acc[r][1], acc[r][2], acc[r][3]);
        *(float4*)(Y + (size_t)(row0 + r) * F + tx * 4) = o;
    }
}

// --- counting sort by destination -------------------------------------------

__global__ __launch_bounds__(256) void hist_dst(const int* __restrict__ ei,
                                                int* __restrict__ counts, int E) {
    for (int e = blockIdx.x * 256 + threadIdx.x; e < E; e += gridDim.x * 256)
        atomicAdd(&counts[ei[E + e]], 1);
}

// Stage 1: per-block (1024-count chunk) sum -> bsum[b]
__global__ __launch_bounds__(256) void scan_pass1(const int* __restrict__ counts,
                                                  int* __restrict__ bsum, int n) {
    __shared__ int sh[256];
    const int base = blockIdx.x * 1024 + threadIdx.x * 4;
    int s = 0;
#pragma unroll
    for (int j = 0; j < 4; ++j) {
        const int i = base + j;
        if (i < n) s += counts[i];
    }
    sh[threadIdx.x] = s;
    __syncthreads();
    for (int off = 128; off > 0; off >>= 1) {
        if (threadIdx.x < off) sh[threadIdx.x] += sh[threadIdx.x + off];
        __syncthreads();
    }
    if (threadIdx.x == 0) bsum[blockIdx.x] = sh[0];
}

// Stage 2: single small block, exclusive scan of nb block sums; bsum[nb] = total.
__global__ __launch_bounds__(256) void scan_pass2(int* __restrict__ bsum, int nb) {
    __shared__ int sh[256];
    int v = (threadIdx.x < nb) ? bsum[threadIdx.x] : 0;
    sh[threadIdx.x] = v;
    __syncthreads();
    // Hillis-Steele inclusive scan
    for (int off = 1; off < 256; off <<= 1) {
        int t = (threadIdx.x >= off) ? sh[threadIdx.x - off] : 0;
        __syncthreads();
        sh[threadIdx.x] += t;
        __syncthreads();
    }
    if (threadIdx.x < nb) bsum[threadIdx.x] = sh[threadIdx.x] - v;  // exclusive
    if (threadIdx.x == nb) bsum[nb] = sh[nb - 1];                   // total
}

// Stage 3: recompute local exclusive prefix, add block base, write offs+cursor.
__global__ __launch_bounds__(256) void scan_pass3(const int* __restrict__ counts,
                                                  const int* __restrict__ bsum,
                                                  int* __restrict__ offs,
                                                  int* __restrict__ cursor,
                                                  int n, int nb) {
    __shared__ int sh[256];
    const int base = blockIdx.x * 1024 + threadIdx.x * 4;
    int c[4];
    int s = 0;
#pragma unroll
    for (int j = 0; j < 4; ++j) {
        const int i = base + j;
        c[j] = (i < n) ? counts[i] : 0;
        s += c[j];
    }
    int inc = s;
    sh[threadIdx.x] = inc;
    __syncthreads();
    for (int off = 1; off < 256; off <<= 1) {
        int t = (threadIdx.x >= off) ? sh[threadIdx.x - off] : 0;
        __syncthreads();
        sh[threadIdx.x] += t;
        __syncthreads();
    }
    int run = bsum[blockIdx.x] + sh[threadIdx.x] - inc;  // exclusive thread base
#pragma unroll
    for (int j = 0; j < 4; ++j) {
        const int i = base + j;
        if (i < n) { offs[i] = run; cursor[i] = run; }
        run += c[j];
    }
    if (blockIdx.x == 0 && threadIdx.x == 0) offs[n] = bsum[nb];
}

__global__ __launch_bounds__(256) void bucket_fill(const int* __restrict__ ei,
                                                   const float* __restrict__ ew,
                                                   int* __restrict__ cursor,
                                                   int* __restrict__ Ssrc,
                                                   float* __restrict__ Sw, int E) {
    const int e = blockIdx.x * 256 + threadIdx.x;
    if (e >= E) return;
    const int dst = ei[E + e];
    const int slot = atomicAdd(&cursor[dst], 1);
    Ssrc[slot] = ei[e];
    Sw[slot] = ew[e];
}

// OUT[v] = sum over incoming edges w_e * XW[src_e]; 32 lanes per node, no atomics.
__global__ __launch_bounds__(256) void gather_agg(const float* __restrict__ XW,
                                                  const int* __restrict__ offs,
                                                  const int* __restrict__ Ssrc,
                                                  const float* __restrict__ Sw,
                                                  float* __restrict__ OUT, int n) {
    const int l = threadIdx.x & 31;
    const int v = blockIdx.x * 8 + (threadIdx.x >> 5);
    if (v >= n) return;
    float4 acc = make_float4(0.f, 0.f, 0.f, 0.f);
    const int b = offs[v], e2 = offs[v + 1];
    for (int p = b; p < e2; ++p) {
        const int s = Ssrc[p];
        const float w = Sw[p];
        const float4 x = ((const float4*)(XW + (size_t)s * F))[l];
        acc.x = fmaf(w, x.x, acc.x);
        acc.y = fmaf(w, x.y, acc.y);
        acc.z = fmaf(w, x.z, acc.z);
        acc.w = fmaf(w, x.w, acc.w);
    }
    ((float4*)(OUT + (size_t)v * F))[l] = acc;
}

// out[p,:] = [Z[a], Z[b]] @ Wlin^T ; one 64-lane wave per pair.
__global__ __launch_bounds__(256) void pair_lin(const float* __restrict__ Z,
                                                const int* __restrict__ pos,
                                                const float* __restrict__ Wlin,
                                                float* __restrict__ out, int P) {
    __shared__ float WL[512];
    for (int i = threadIdx.x; i < 512; i += 256) WL[i] = Wlin[i];
    __syncthreads();

    const int lane = threadIdx.x & 63;
    const int p = blockIdx.x * 4 + (threadIdx.x >> 6);
    if (p >= P) return;
    const int a = pos[p];
    const int b = pos[P + p];
    float2 zi = ((const float2*)(Z + (size_t)a * F))[lane];
    float2 zj = ((const float2*)(Z + (size_t)b * F))[lane];
    const int k = lane * 2;
    float acc0 = zi.x * WL[k]       + zi.y * WL[k + 1]
               + zj.x * WL[128 + k] + zj.y * WL[128 + k + 1];
    float acc1 = zi.x * WL[256 + k] + zi.y * WL[256 + k + 1]
               + zj.x * WL[384 + k] + zj.y * WL[384 + k + 1];
#pragma unroll
    for (int off = 32; off > 0; off >>= 1) {
        acc0 += __shfl_down(acc0, off, 64);
        acc1 += __shfl_down(acc1, off, 64);
    }
    if (lane == 0) {
        out[(size_t)p * 2 + 0] = acc0;
        out[(size_t)p * 2 + 1] = acc1;
    }
}

extern "C" void kernel_launch(void* const* d_in, const int* in_sizes, int n_in,
                              void* d_out, int out_size, void* d_ws, size_t ws_size,
                              hipStream_t stream) {
    const float* x    = (const float*)d_in[0];
    const int*   ei1  = (const int*)  d_in[1];
    const int*   ei2  = (const int*)  d_in[2];
    const float* ew1  = (const float*)d_in[3];
    const float* ew2  = (const float*)d_in[4];
    const int*   pos  = (const int*)  d_in[5];
    const float* W1   = (const float*)d_in[6];
    const float* W2   = (const float*)d_in[7];
    const float* Wlin = (const float*)d_in[8];
    float* out = (float*)d_out;

    const int N  = in_sizes[0] / F;
    const int E1 = in_sizes[1] / 2;
    const int E2 = in_sizes[2] / 2;
    const int P  = in_sizes[5] / 2;
    const int Emax = E1 > E2 ? E1 : E2;
    const int NB = (N + 1023) / 1024;   // scan blocks (<= 256 required; 98 for N=100k)

    // workspace layout
    float* A      = (float*)d_ws;                 // N x 128
    float* B      = A + (size_t)N * F;            // N x 128
    int*   counts = (int*)(B + (size_t)N * F);    // N
    int*   offs   = counts + N;                   // N+1
    int*   cursor = offs + N + 1;                 // N
    int*   bsum   = cursor + N;                   // NB+1
    int*   Ssrc   = bsum + NB + 1;                // Emax
    float* Sw     = (float*)(Ssrc + Emax);        // Emax

    // ---- layer 1: A = x @ W1 ; B = segment_sum over edges1 ----
    gemm128<<<(N + 31) / 32, 256, 0, stream>>>(x, W1, A, N, 0);

    hipMemsetAsync(counts, 0, (size_t)N * sizeof(int), stream);
    hist_dst<<<1024, 256, 0, stream>>>(ei1, counts, E1);
    scan_pass1<<<NB, 256, 0, stream>>>(counts, bsum, N);
    scan_pass2<<<1, 256, 0, stream>>>(bsum, NB);
    scan_pass3<<<NB, 256, 0, stream>>>(counts, bsum, offs, cursor, N, NB);
    bucket_fill<<<(E1 + 255) / 256, 256, 0, stream>>>(ei1, ew1, cursor, Ssrc, Sw, E1);
    gather_agg<<<(N + 7) / 8, 256, 0, stream>>>(A, offs, Ssrc, Sw, B, N);

    // ---- layer 2: A = relu(B) @ W2 ; B = segment_sum over edges2 ----
    gemm128<<<(N + 31) / 32, 256, 0, stream>>>(B, W2, A, N, 1);

    hipMemsetAsync(counts, 0, (size_t)N * sizeof(int), stream);
    hist_dst<<<1024, 256, 0, stream>>>(ei2, counts, E2);
    scan_pass1<<<NB, 256, 0, stream>>>(counts, bsum, N);
    scan_pass2<<<1, 256, 0, stream>>>(bsum, NB);
    scan_pass3<<<NB, 256, 0, stream>>>(counts, bsum, offs, cursor, N, NB);
    bucket_fill<<<(E2 + 255) / 256, 256, 0, stream>>>(ei2, ew2, cursor, Ssrc, Sw, E2);
    gather_agg<<<(N + 7) / 8, 256, 0, stream>>>(A, offs, Ssrc, Sw, B, N);

    // ---- head ----
    pair_lin<<<(P + 3) / 4, 256, 0, stream>>>(B, pos, Wlin, out, P);
}

// Round 4
// 633.623 us; speedup vs baseline: 4.8711x; 1.1222x over previous
//
#include <hip/hip_runtime.h>

#define F 128

// Y[n,128] = act(X[n,128]) @ W[128,128]; act = relu if RELU.
// Block: 256 threads; tx = col group (4 cols), ty = row group (8 rows) -> 64 rows/block.
// W staged whole in LDS (64 KB); X prefetched one k-chunk ahead (ping-pong).
template <int RELU>
__global__ __launch_bounds__(256) void gemm128(const float* __restrict__ X,
                                               const float* __restrict__ W,
                                               float* __restrict__ Y,
                                               int n) {
    __shared__ float WL[F * F];                    // 64 KB
    const float4* __restrict__ Wv = (const float4*)W;
    float4* WL4 = (float4*)WL;
    for (int i = threadIdx.x; i < F * F / 4; i += 256) WL4[i] = Wv[i];
    __syncthreads();

    const int tx = threadIdx.x & 31;               // cols [4tx, 4tx+3]
    const int ty = threadIdx.x >> 5;               // rows [row0, row0+7]
    const int row0 = blockIdx.x * 64 + ty * 8;

    float acc[8][4];
#pragma unroll
    for (int r = 0; r < 8; ++r)
#pragma unroll
        for (int c = 0; c < 4; ++c) acc[r][c] = 0.f;

    // clamped row indices so last partial block loads stay in bounds
    int rr[8];
#pragma unroll
    for (int r = 0; r < 8; ++r) rr[r] = min(row0 + r, n - 1);

    float4 xa[8], xb[8];
#pragma unroll
    for (int r = 0; r < 8; ++r) {
        float4 v = *(const float4*)(X + (size_t)rr[r] * F);
        if (RELU) {
            v.x = fmaxf(v.x, 0.f); v.y = fmaxf(v.y, 0.f);
            v.z = fmaxf(v.z, 0.f); v.w = fmaxf(v.w, 0.f);
        }
        xa[r] = v;
    }

    for (int k = 0; k < F; k += 4) {
        if (k + 4 < F) {
#pragma unroll
            for (int r = 0; r < 8; ++r) {
                float4 v = *(const float4*)(X + (size_t)rr[r] * F + k + 4);
                if (RELU) {
                    v.x = fmaxf(v.x, 0.f); v.y = fmaxf(v.y, 0.f);
                    v.z = fmaxf(v.z, 0.f); v.w = fmaxf(v.w, 0.f);
                }
                xb[r] = v;
            }
        }
#pragma unroll
        for (int kk = 0; kk < 4; ++kk) {
            const float4 w = ((const float4*)WL)[(size_t)(k + kk) * 32 + tx];
#pragma unroll
            for (int r = 0; r < 8; ++r) {
                const float xs = ((const float*)&xa[r])[kk];
                acc[r][0] = fmaf(xs, w.x, acc[r][0]);
                acc[r][1] = fmaf(xs, w.y, acc[r][1]);
                acc[r][2] = fmaf(xs, w.z, acc[r][2]);
                acc[r][3] = fmaf(xs, w.w, acc[r][3]);
            }
        }
        if (k + 4 < F) {
#pragma unroll
            for (int r = 0; r < 8; ++r) xa[r] = xb[r];
        }
    }
#pragma unroll
    for (int r = 0; r < 8; ++r) {
        if (row0 + r < n) {
            float4 o = make_float4(acc[r][0], acc[r][1], acc[r][2], acc[r][3]);
            *(float4*)(Y + (size_t)(row0 + r) * F + tx * 4) = o;
        }
    }
}

// --- counting sort by destination -------------------------------------------

__global__ __launch_bounds__(256) void hist_dst(const int* __restrict__ ei,
                                                int* __restrict__ counts, int E) {
    for (int e = blockIdx.x * 256 + threadIdx.x; e < E; e += gridDim.x * 256)
        atomicAdd(&counts[ei[E + e]], 1);
}

// Stage 1: per-block (1024-count chunk) sum -> bsum[b]
__global__ __launch_bounds__(256) void scan_pass1(const int* __restrict__ counts,
                                                  int* __restrict__ bsum, int n) {
    __shared__ int sh[256];
    const int base = blockIdx.x * 1024 + threadIdx.x * 4;
    int s = 0;
#pragma unroll
    for (int j = 0; j < 4; ++j) {
        const int i = base + j;
        if (i < n) s += counts[i];
    }
    sh[threadIdx.x] = s;
    __syncthreads();
    for (int off = 128; off > 0; off >>= 1) {
        if (threadIdx.x < off) sh[threadIdx.x] += sh[threadIdx.x + off];
        __syncthreads();
    }
    if (threadIdx.x == 0) bsum[blockIdx.x] = sh[0];
}

// Stage 2: single small block, exclusive scan of nb block sums; bsum[nb] = total.
__global__ __launch_bounds__(256) void scan_pass2(int* __restrict__ bsum, int nb) {
    __shared__ int sh[256];
    int v = (threadIdx.x < nb) ? bsum[threadIdx.x] : 0;
    sh[threadIdx.x] = v;
    __syncthreads();
    for (int off = 1; off < 256; off <<= 1) {
        int t = (threadIdx.x >= off) ? sh[threadIdx.x - off] : 0;
        __syncthreads();
        sh[threadIdx.x] += t;
        __syncthreads();
    }
    if (threadIdx.x < nb) bsum[threadIdx.x] = sh[threadIdx.x] - v;  // exclusive
    if (threadIdx.x == nb) bsum[nb] = sh[nb - 1];                   // total
}

// Stage 3: recompute local exclusive prefix, add block base, write offs+cursor.
__global__ __launch_bounds__(256) void scan_pass3(const int* __restrict__ counts,
                                                  const int* __restrict__ bsum,
                                                  int* __restrict__ offs,
                                                  int* __restrict__ cursor,
                                                  int n, int nb) {
    __shared__ int sh[256];
    const int base = blockIdx.x * 1024 + threadIdx.x * 4;
    int c[4];
    int s = 0;
#pragma unroll
    for (int j = 0; j < 4; ++j) {
        const int i = base + j;
        c[j] = (i < n) ? counts[i] : 0;
        s += c[j];
    }
    int inc = s;
    sh[threadIdx.x] = inc;
    __syncthreads();
    for (int off = 1; off < 256; off <<= 1) {
        int t = (threadIdx.x >= off) ? sh[threadIdx.x - off] : 0;
        __syncthreads();
        sh[threadIdx.x] += t;
        __syncthreads();
    }
    int run = bsum[blockIdx.x] + sh[threadIdx.x] - inc;
#pragma unroll
    for (int j = 0; j < 4; ++j) {
        const int i = base + j;
        if (i < n) { offs[i] = run; cursor[i] = run; }
        run += c[j];
    }
    if (blockIdx.x == 0 && threadIdx.x == 0) offs[n] = bsum[nb];
}

// Pack (src, weight-bits) into one int2 per edge slot.
__global__ __launch_bounds__(256) void bucket_fill(const int* __restrict__ ei,
                                                   const float* __restrict__ ew,
                                                   int* __restrict__ cursor,
                                                   int2* __restrict__ Sedge, int E) {
    const int e = blockIdx.x * 256 + threadIdx.x;
    if (e >= E) return;
    const int dst = ei[E + e];
    const int slot = atomicAdd(&cursor[dst], 1);
    Sedge[slot] = make_int2(ei[e], __float_as_int(ew[e]));
}

// OUT[v] = sum over incoming edges w_e * XW[src_e]; 32 lanes per node, no atomics.
// Edge loop unrolled x4 so 4 row-loads are in flight at once.
__global__ __launch_bounds__(256) void gather_agg(const float* __restrict__ XW,
                                                  const int* __restrict__ offs,
                                                  const int2* __restrict__ Sedge,
                                                  float* __restrict__ OUT, int n) {
    const int l = threadIdx.x & 31;
    const int v = blockIdx.x * 8 + (threadIdx.x >> 5);
    if (v >= n) return;
    float4 acc = make_float4(0.f, 0.f, 0.f, 0.f);
    const int b = offs[v], e2 = offs[v + 1];
    int p = b;
    for (; p + 4 <= e2; p += 4) {
        const int2 s0 = Sedge[p],     s1 = Sedge[p + 1];
        const int2 s2 = Sedge[p + 2], s3 = Sedge[p + 3];
        const float4 x0 = ((const float4*)(XW + (size_t)s0.x * F))[l];
        const float4 x1 = ((const float4*)(XW + (size_t)s1.x * F))[l];
        const float4 x2 = ((const float4*)(XW + (size_t)s2.x * F))[l];
        const float4 x3 = ((const float4*)(XW + (size_t)s3.x * F))[l];
        const float w0 = __int_as_float(s0.y), w1 = __int_as_float(s1.y);
        const float w2 = __int_as_float(s2.y), w3 = __int_as_float(s3.y);
        acc.x = fmaf(w0, x0.x, acc.x); acc.y = fmaf(w0, x0.y, acc.y);
        acc.z = fmaf(w0, x0.z, acc.z); acc.w = fmaf(w0, x0.w, acc.w);
        acc.x = fmaf(w1, x1.x, acc.x); acc.y = fmaf(w1, x1.y, acc.y);
        acc.z = fmaf(w1, x1.z, acc.z); acc.w = fmaf(w1, x1.w, acc.w);
        acc.x = fmaf(w2, x2.x, acc.x); acc.y = fmaf(w2, x2.y, acc.y);
        acc.z = fmaf(w2, x2.z, acc.z); acc.w = fmaf(w2, x2.w, acc.w);
        acc.x = fmaf(w3, x3.x, acc.x); acc.y = fmaf(w3, x3.y, acc.y);
        acc.z = fmaf(w3, x3.z, acc.z); acc.w = fmaf(w3, x3.w, acc.w);
    }
    for (; p < e2; ++p) {
        const int2 s = Sedge[p];
        const float w = __int_as_float(s.y);
        const float4 x = ((const float4*)(XW + (size_t)s.x * F))[l];
        acc.x = fmaf(w, x.x, acc.x); acc.y = fmaf(w, x.y, acc.y);
        acc.z = fmaf(w, x.z, acc.z); acc.w = fmaf(w, x.w, acc.w);
    }
    ((float4*)(OUT + (size_t)v * F))[l] = acc;
}

// out[p,:] = [Z[a], Z[b]] @ Wlin^T ; one 64-lane wave per pair.
__global__ __launch_bounds__(256) void pair_lin(const float* __restrict__ Z,
                                                const int* __restrict__ pos,
                                                const float* __restrict__ Wlin,
                                                float* __restrict__ out, int P) {
    __shared__ float WL[512];
    for (int i = threadIdx.x; i < 512; i += 256) WL[i] = Wlin[i];
    __syncthreads();

    const int lane = threadIdx.x & 63;
    const int p = blockIdx.x * 4 + (threadIdx.x >> 6);
    if (p >= P) return;
    const int a = pos[p];
    const int b = pos[P + p];
    float2 zi = ((const float2*)(Z + (size_t)a * F))[lane];
    float2 zj = ((const float2*)(Z + (size_t)b * F))[lane];
    const int k = lane * 2;
    float acc0 = zi.x * WL[k]       + zi.y * WL[k + 1]
               + zj.x * WL[128 + k] + zj.y * WL[128 + k + 1];
    float acc1 = zi.x * WL[256 + k] + zi.y * WL[256 + k + 1]
               + zj.x * WL[384 + k] + zj.y * WL[384 + k + 1];
#pragma unroll
    for (int off = 32; off > 0; off >>= 1) {
        acc0 += __shfl_down(acc0, off, 64);
        acc1 += __shfl_down(acc1, off, 64);
    }
    if (lane == 0) {
        out[(size_t)p * 2 + 0] = acc0;
        out[(size_t)p * 2 + 1] = acc1;
    }
}

extern "C" void kernel_launch(void* const* d_in, const int* in_sizes, int n_in,
                              void* d_out, int out_size, void* d_ws, size_t ws_size,
                              hipStream_t stream) {
    const float* x    = (const float*)d_in[0];
    const int*   ei1  = (const int*)  d_in[1];
    const int*   ei2  = (const int*)  d_in[2];
    const float* ew1  = (const float*)d_in[3];
    const float* ew2  = (const float*)d_in[4];
    const int*   pos  = (const int*)  d_in[5];
    const float* W1   = (const float*)d_in[6];
    const float* W2   = (const float*)d_in[7];
    const float* Wlin = (const float*)d_in[8];
    float* out = (float*)d_out;

    const int N  = in_sizes[0] / F;
    const int E1 = in_sizes[1] / 2;
    const int E2 = in_sizes[2] / 2;
    const int P  = in_sizes[5] / 2;
    const int Emax = E1 > E2 ? E1 : E2;
    const int NB = (N + 1023) / 1024;   // <= 256 required; 98 for N=100k

    // workspace layout
    float* A      = (float*)d_ws;                 // N x 128
    float* B      = A + (size_t)N * F;            // N x 128
    int*   counts = (int*)(B + (size_t)N * F);    // N
    int*   offs   = counts + N;                   // N+1
    int*   cursor = offs + N + 1;                 // N
    int*   bsum   = cursor + N;                   // NB+1
    uintptr_t sp  = (uintptr_t)(bsum + NB + 1);
    sp = (sp + 7) & ~(uintptr_t)7;
    int2*  Sedge  = (int2*)sp;                    // Emax (8 B each)

    // ---- layer 1: A = x @ W1 ; B = segment_sum over edges1 ----
    gemm128<0><<<(N + 63) / 64, 256, 0, stream>>>(x, W1, A, N);

    hipMemsetAsync(counts, 0, (size_t)N * sizeof(int), stream);
    hist_dst<<<1024, 256, 0, stream>>>(ei1, counts, E1);
    scan_pass1<<<NB, 256, 0, stream>>>(counts, bsum, N);
    scan_pass2<<<1, 256, 0, stream>>>(bsum, NB);
    scan_pass3<<<NB, 256, 0, stream>>>(counts, bsum, offs, cursor, N, NB);
    bucket_fill<<<(E1 + 255) / 256, 256, 0, stream>>>(ei1, ew1, cursor, Sedge, E1);
    gather_agg<<<(N + 7) / 8, 256, 0, stream>>>(A, offs, Sedge, B, N);

    // ---- layer 2: A = relu(B) @ W2 ; B = segment_sum over edges2 ----
    gemm128<1><<<(N + 63) / 64, 256, 0, stream>>>(B, W2, A, N);

    hipMemsetAsync(counts, 0, (size_t)N * sizeof(int), stream);
    hist_dst<<<1024, 256, 0, stream>>>(ei2, counts, E2);
    scan_pass1<<<NB, 256, 0, stream>>>(counts, bsum, N);
    scan_pass2<<<1, 256, 0, stream>>>(bsum, NB);
    scan_pass3<<<NB, 256, 0, stream>>>(counts, bsum, offs, cursor, N, NB);
    bucket_fill<<<(E2 + 255) / 256, 256, 0, stream>>>(ei2, ew2, cursor, Sedge, E2);
    gather_agg<<<(N + 7) / 8, 256, 0, stream>>>(A, offs, Sedge, B, N);

    // ---- head ----
    pair_lin<<<(P + 3) / 4, 256, 0, stream>>>(B, pos, Wlin, out, P);
}

// Round 5
// 507.004 us; speedup vs baseline: 6.0876x; 1.2497x over previous
//
#include <hip/hip_runtime.h>

#define F 128

typedef __bf16 bf16x8 __attribute__((ext_vector_type(8)));
typedef unsigned short ushort8 __attribute__((ext_vector_type(8)));
typedef float f32x4 __attribute__((ext_vector_type(4)));

// fp32 -> bf16 with round-to-nearest-even (int ops only; inputs finite).
static __device__ __forceinline__ unsigned short f2bf(float f) {
    unsigned int u = __float_as_uint(f);
    u += 0x7fffu + ((u >> 16) & 1u);
    return (unsigned short)(u >> 16);
}

#define WPITCH 136  // ushorts per WT row: 128 + 8 pad (keeps 16B align, breaks pow2 bank stride)

// Y[n,128] = act(X[n,128]) @ W[128,128] via bf16 MFMA, fp32 accumulate.
// Block: 4 waves x 32 rows = 128 rows. W^T staged in LDS as bf16 once per block.
template <int RELU>
__global__ __launch_bounds__(256) void gemm128_mfma(const float* __restrict__ X,
                                                    const float* __restrict__ W,
                                                    float* __restrict__ Y,
                                                    int n) {
    __shared__ __align__(16) unsigned short WT[F * WPITCH];  // WT[col][k], bf16 bits
    for (int idx = threadIdx.x; idx < F * F; idx += 256) {
        const int k = idx >> 7, c = idx & 127;
        WT[c * WPITCH + k] = f2bf(W[idx]);
    }
    __syncthreads();

    const int lane = threadIdx.x & 63;
    const int wv = threadIdx.x >> 6;
    const int m15 = lane & 15;
    const int quad = lane >> 4;
    const int rowBase = blockIdx.x * 128 + wv * 32;

    f32x4 acc[2][8];
#pragma unroll
    for (int rt = 0; rt < 2; ++rt)
#pragma unroll
        for (int ct = 0; ct < 8; ++ct) acc[rt][ct] = (f32x4){0.f, 0.f, 0.f, 0.f};

    int rA[2];
    rA[0] = min(rowBase + m15, n - 1);        // clamped; stores masked below
    rA[1] = min(rowBase + 16 + m15, n - 1);

#pragma unroll
    for (int ks = 0; ks < 4; ++ks) {
        const int k0 = ks * 32 + quad * 8;    // this lane's 8-wide k window
        bf16x8 a[2];
#pragma unroll
        for (int rt = 0; rt < 2; ++rt) {
            const float* p = X + (size_t)rA[rt] * F + k0;
            float4 lo = *(const float4*)p;
            float4 hi = *(const float4*)(p + 4);
            if (RELU) {
                lo.x = fmaxf(lo.x, 0.f); lo.y = fmaxf(lo.y, 0.f);
                lo.z = fmaxf(lo.z, 0.f); lo.w = fmaxf(lo.w, 0.f);
                hi.x = fmaxf(hi.x, 0.f); hi.y = fmaxf(hi.y, 0.f);
                hi.z = fmaxf(hi.z, 0.f); hi.w = fmaxf(hi.w, 0.f);
            }
            ushort8 u;
            u[0] = f2bf(lo.x); u[1] = f2bf(lo.y); u[2] = f2bf(lo.z); u[3] = f2bf(lo.w);
            u[4] = f2bf(hi.x); u[5] = f2bf(hi.y); u[6] = f2bf(hi.z); u[7] = f2bf(hi.w);
            a[rt] = __builtin_bit_cast(bf16x8, u);
        }
#pragma unroll
        for (int ct = 0; ct < 8; ++ct) {
            const int nn = ct * 16 + m15;
            const bf16x8 b = *(const bf16x8*)(WT + nn * WPITCH + k0);  // ds_read_b128
            acc[0][ct] = __builtin_amdgcn_mfma_f32_16x16x32_bf16(a[0], b, acc[0][ct], 0, 0, 0);
            acc[1][ct] = __builtin_amdgcn_mfma_f32_16x16x32_bf16(a[1], b, acc[1][ct], 0, 0, 0);
        }
    }

    // C/D layout: col = lane&15, row = quad*4 + reg (within each 16x16 tile)
#pragma unroll
    for (int rt = 0; rt < 2; ++rt)
#pragma unroll
        for (int reg = 0; reg < 4; ++reg) {
            const int row = rowBase + rt * 16 + quad * 4 + reg;
            if (row < n) {
#pragma unroll
                for (int ct = 0; ct < 8; ++ct)
                    Y[(size_t)row * F + ct * 16 + m15] = acc[rt][ct][reg];
            }
        }
}

// --- counting sort by destination -------------------------------------------

__global__ __launch_bounds__(256) void hist_dst(const int* __restrict__ ei,
                                                int* __restrict__ counts, int E) {
    for (int e = blockIdx.x * 256 + threadIdx.x; e < E; e += gridDim.x * 256)
        atomicAdd(&counts[ei[E + e]], 1);
}

__global__ __launch_bounds__(256) void scan_pass1(const int* __restrict__ counts,
                                                  int* __restrict__ bsum, int n) {
    __shared__ int sh[256];
    const int base = blockIdx.x * 1024 + threadIdx.x * 4;
    int s = 0;
#pragma unroll
    for (int j = 0; j < 4; ++j) {
        const int i = base + j;
        if (i < n) s += counts[i];
    }
    sh[threadIdx.x] = s;
    __syncthreads();
    for (int off = 128; off > 0; off >>= 1) {
        if (threadIdx.x < off) sh[threadIdx.x] += sh[threadIdx.x + off];
        __syncthreads();
    }
    if (threadIdx.x == 0) bsum[blockIdx.x] = sh[0];
}

__global__ __launch_bounds__(256) void scan_pass2(int* __restrict__ bsum, int nb) {
    __shared__ int sh[256];
    int v = (threadIdx.x < nb) ? bsum[threadIdx.x] : 0;
    sh[threadIdx.x] = v;
    __syncthreads();
    for (int off = 1; off < 256; off <<= 1) {
        int t = (threadIdx.x >= off) ? sh[threadIdx.x - off] : 0;
        __syncthreads();
        sh[threadIdx.x] += t;
        __syncthreads();
    }
    if (threadIdx.x < nb) bsum[threadIdx.x] = sh[threadIdx.x] - v;  // exclusive
    if (threadIdx.x == nb) bsum[nb] = sh[nb - 1];                   // total
}

__global__ __launch_bounds__(256) void scan_pass3(const int* __restrict__ counts,
                                                  const int* __restrict__ bsum,
                                                  int* __restrict__ offs,
                                                  int* __restrict__ cursor,
                                                  int n, int nb) {
    __shared__ int sh[256];
    const int base = blockIdx.x * 1024 + threadIdx.x * 4;
    int c[4];
    int s = 0;
#pragma unroll
    for (int j = 0; j < 4; ++j) {
        const int i = base + j;
        c[j] = (i < n) ? counts[i] : 0;
        s += c[j];
    }
    int inc = s;
    sh[threadIdx.x] = inc;
    __syncthreads();
    for (int off = 1; off < 256; off <<= 1) {
        int t = (threadIdx.x >= off) ? sh[threadIdx.x - off] : 0;
        __syncthreads();
        sh[threadIdx.x] += t;
        __syncthreads();
    }
    int run = bsum[blockIdx.x] + sh[threadIdx.x] - inc;
#pragma unroll
    for (int j = 0; j < 4; ++j) {
        const int i = base + j;
        if (i < n) { offs[i] = run; cursor[i] = run; }
        run += c[j];
    }
    if (blockIdx.x == 0 && threadIdx.x == 0) offs[n] = bsum[nb];
}

__global__ __launch_bounds__(256) void bucket_fill(const int* __restrict__ ei,
                                                   const float* __restrict__ ew,
                                                   int* __restrict__ cursor,
                                                   int2* __restrict__ Sedge, int E) {
    const int e = blockIdx.x * 256 + threadIdx.x;
    if (e >= E) return;
    const int dst = ei[E + e];
    const int slot = atomicAdd(&cursor[dst], 1);
    Sedge[slot] = make_int2(ei[e], __float_as_int(ew[e]));
}

// OUT[v] = sum over incoming edges w_e * XW[src_e]; 32 lanes per node, no atomics.
__global__ __launch_bounds__(256) void gather_agg(const float* __restrict__ XW,
                                                  const int* __restrict__ offs,
                                                  const int2* __restrict__ Sedge,
                                                  float* __restrict__ OUT, int n) {
    const int l = threadIdx.x & 31;
    const int v = blockIdx.x * 8 + (threadIdx.x >> 5);
    if (v >= n) return;
    float4 acc = make_float4(0.f, 0.f, 0.f, 0.f);
    const int b = offs[v], e2 = offs[v + 1];
    int p = b;
    for (; p + 4 <= e2; p += 4) {
        const int2 s0 = Sedge[p],     s1 = Sedge[p + 1];
        const int2 s2 = Sedge[p + 2], s3 = Sedge[p + 3];
        const float4 x0 = ((const float4*)(XW + (size_t)s0.x * F))[l];
        const float4 x1 = ((const float4*)(XW + (size_t)s1.x * F))[l];
        const float4 x2 = ((const float4*)(XW + (size_t)s2.x * F))[l];
        const float4 x3 = ((const float4*)(XW + (size_t)s3.x * F))[l];
        const float w0 = __int_as_float(s0.y), w1 = __int_as_float(s1.y);
        const float w2 = __int_as_float(s2.y), w3 = __int_as_float(s3.y);
        acc.x = fmaf(w0, x0.x, acc.x); acc.y = fmaf(w0, x0.y, acc.y);
        acc.z = fmaf(w0, x0.z, acc.z); acc.w = fmaf(w0, x0.w, acc.w);
        acc.x = fmaf(w1, x1.x, acc.x); acc.y = fmaf(w1, x1.y, acc.y);
        acc.z = fmaf(w1, x1.z, acc.z); acc.w = fmaf(w1, x1.w, acc.w);
        acc.x = fmaf(w2, x2.x, acc.x); acc.y = fmaf(w2, x2.y, acc.y);
        acc.z = fmaf(w2, x2.z, acc.z); acc.w = fmaf(w2, x2.w, acc.w);
        acc.x = fmaf(w3, x3.x, acc.x); acc.y = fmaf(w3, x3.y, acc.y);
        acc.z = fmaf(w3, x3.z, acc.z); acc.w = fmaf(w3, x3.w, acc.w);
    }
    for (; p < e2; ++p) {
        const int2 s = Sedge[p];
        const float w = __int_as_float(s.y);
        const float4 x = ((const float4*)(XW + (size_t)s.x * F))[l];
        acc.x = fmaf(w, x.x, acc.x); acc.y = fmaf(w, x.y, acc.y);
        acc.z = fmaf(w, x.z, acc.z); acc.w = fmaf(w, x.w, acc.w);
    }
    ((float4*)(OUT + (size_t)v * F))[l] = acc;
}

// out[p,:] = [Z[a], Z[b]] @ Wlin^T ; one 64-lane wave per pair.
__global__ __launch_bounds__(256) void pair_lin(const float* __restrict__ Z,
                                                const int* __restrict__ pos,
                                                const float* __restrict__ Wlin,
                                                float* __restrict__ out, int P) {
    __shared__ float WL[512];
    for (int i = threadIdx.x; i < 512; i += 256) WL[i] = Wlin[i];
    __syncthreads();

    const int lane = threadIdx.x & 63;
    const int p = blockIdx.x * 4 + (threadIdx.x >> 6);
    if (p >= P) return;
    const int a = pos[p];
    const int b = pos[P + p];
    float2 zi = ((const float2*)(Z + (size_t)a * F))[lane];
    float2 zj = ((const float2*)(Z + (size_t)b * F))[lane];
    const int k = lane * 2;
    float acc0 = zi.x * WL[k]       + zi.y * WL[k + 1]
               + zj.x * WL[128 + k] + zj.y * WL[128 + k + 1];
    float acc1 = zi.x * WL[256 + k] + zi.y * WL[256 + k + 1]
               + zj.x * WL[384 + k] + zj.y * WL[384 + k + 1];
#pragma unroll
    for (int off = 32; off > 0; off >>= 1) {
        acc0 += __shfl_down(acc0, off, 64);
        acc1 += __shfl_down(acc1, off, 64);
    }
    if (lane == 0) {
        out[(size_t)p * 2 + 0] = acc0;
        out[(size_t)p * 2 + 1] = acc1;
    }
}

extern "C" void kernel_launch(void* const* d_in, const int* in_sizes, int n_in,
                              void* d_out, int out_size, void* d_ws, size_t ws_size,
                              hipStream_t stream) {
    const float* x    = (const float*)d_in[0];
    const int*   ei1  = (const int*)  d_in[1];
    const int*   ei2  = (const int*)  d_in[2];
    const float* ew1  = (const float*)d_in[3];
    const float* ew2  = (const float*)d_in[4];
    const int*   pos  = (const int*)  d_in[5];
    const float* W1   = (const float*)d_in[6];
    const float* W2   = (const float*)d_in[7];
    const float* Wlin = (const float*)d_in[8];
    float* out = (float*)d_out;

    const int N  = in_sizes[0] / F;
    const int E1 = in_sizes[1] / 2;
    const int E2 = in_sizes[2] / 2;
    const int P  = in_sizes[5] / 2;
    const int Emax = E1 > E2 ? E1 : E2;
    const int NB = (N + 1023) / 1024;   // <= 256 required; 98 for N=100k

    // workspace layout
    float* A      = (float*)d_ws;                 // N x 128
    float* B      = A + (size_t)N * F;            // N x 128
    int*   counts = (int*)(B + (size_t)N * F);    // N
    int*   offs   = counts + N;                   // N+1
    int*   cursor = offs + N + 1;                 // N
    int*   bsum   = cursor + N;                   // NB+1
    uintptr_t sp  = (uintptr_t)(bsum + NB + 1);
    sp = (sp + 7) & ~(uintptr_t)7;
    int2*  Sedge  = (int2*)sp;                    // Emax (8 B each)

    // ---- layer 1: A = x @ W1 ; B = segment_sum over edges1 ----
    gemm128_mfma<0><<<(N + 127) / 128, 256, 0, stream>>>(x, W1, A, N);

    hipMemsetAsync(counts, 0, (size_t)N * sizeof(int), stream);
    hist_dst<<<1024, 256, 0, stream>>>(ei1, counts, E1);
    scan_pass1<<<NB, 256, 0, stream>>>(counts, bsum, N);
    scan_pass2<<<1, 256, 0, stream>>>(bsum, NB);
    scan_pass3<<<NB, 256, 0, stream>>>(counts, bsum, offs, cursor, N, NB);
    bucket_fill<<<(E1 + 255) / 256, 256, 0, stream>>>(ei1, ew1, cursor, Sedge, E1);
    gather_agg<<<(N + 7) / 8, 256, 0, stream>>>(A, offs, Sedge, B, N);

    // ---- layer 2: A = relu(B) @ W2 ; B = segment_sum over edges2 ----
    gemm128_mfma<1><<<(N + 127) / 128, 256, 0, stream>>>(B, W2, A, N);

    hipMemsetAsync(counts, 0, (size_t)N * sizeof(int), stream);
    hist_dst<<<1024, 256, 0, stream>>>(ei2, counts, E2);
    scan_pass1<<<NB, 256, 0, stream>>>(counts, bsum, N);
    scan_pass2<<<1, 256, 0, stream>>>(bsum, NB);
    scan_pass3<<<NB, 256, 0, stream>>>(counts, bsum, offs, cursor, N, NB);
    bucket_fill<<<(E2 + 255) / 256, 256, 0, stream>>>(ei2, ew2, cursor, Sedge, E2);
    gather_agg<<<(N + 7) / 8, 256, 0, stream>>>(A, offs, Sedge, B, N);

    // ---- head ----
    pair_lin<<<(P + 3) / 4, 256, 0, stream>>>(B, pos, Wlin, out, P);
}

// Round 6
// 442.375 us; speedup vs baseline: 6.9769x; 1.1461x over previous
//
#include <hip/hip_runtime.h>

#define F 128

typedef __bf16 bf16x8 __attribute__((ext_vector_type(8)));
typedef unsigned short ushort8 __attribute__((ext_vector_type(8)));
typedef unsigned short ushort4v __attribute__((ext_vector_type(4)));
typedef float f32x4 __attribute__((ext_vector_type(4)));

// fp32 -> bf16 bits with round-to-nearest-even (inputs finite).
static __device__ __forceinline__ unsigned short f2bf(float f) {
    unsigned int u = __float_as_uint(f);
    u += 0x7fffu + ((u >> 16) & 1u);
    return (unsigned short)(u >> 16);
}
// packed uint (2 bf16) -> 2 floats
static __device__ __forceinline__ void bf2x(unsigned int u, float& lo, float& hi) {
    lo = __uint_as_float(u << 16);
    hi = __uint_as_float(u & 0xffff0000u);
}

#define WPITCH 136  // ushorts per WT row: 128 + 8 pad

// Y_bf16[n,128] = act(X[n,128]) @ W[128,128] via bf16 MFMA, fp32 accumulate.
// INBF: X is bf16 (ushort) rows; else fp32. RELU applied to X.
// Block: 4 waves x 32 rows = 128 rows. W^T staged in LDS as bf16 once per block.
template <int RELU, int INBF>
__global__ __launch_bounds__(256) void gemm128_mfma(const void* __restrict__ Xv,
                                                    const float* __restrict__ W,
                                                    unsigned short* __restrict__ Y,
                                                    int n) {
    __shared__ __align__(16) unsigned short WT[F * WPITCH];  // WT[col][k], bf16 bits
    for (int idx = threadIdx.x; idx < F * F; idx += 256) {
        const int k = idx >> 7, c = idx & 127;
        WT[c * WPITCH + k] = f2bf(W[idx]);
    }
    __syncthreads();

    const int lane = threadIdx.x & 63;
    const int wv = threadIdx.x >> 6;
    const int m15 = lane & 15;
    const int quad = lane >> 4;
    const int rowBase = blockIdx.x * 128 + wv * 32;

    f32x4 acc[2][8];
#pragma unroll
    for (int rt = 0; rt < 2; ++rt)
#pragma unroll
        for (int ct = 0; ct < 8; ++ct) acc[rt][ct] = (f32x4){0.f, 0.f, 0.f, 0.f};

    int rA[2];
    rA[0] = min(rowBase + m15, n - 1);        // clamped; stores masked below
    rA[1] = min(rowBase + 16 + m15, n - 1);

#pragma unroll
    for (int ks = 0; ks < 4; ++ks) {
        const int k0 = ks * 32 + quad * 8;    // this lane's 8-wide k window
        bf16x8 a[2];
#pragma unroll
        for (int rt = 0; rt < 2; ++rt) {
            if (INBF) {
                const unsigned short* Xb = (const unsigned short*)Xv;
                ushort8 u = *(const ushort8*)(Xb + (size_t)rA[rt] * F + k0);
                if (RELU) {
#pragma unroll
                    for (int j = 0; j < 8; ++j) u[j] = (u[j] & 0x8000u) ? 0 : u[j];
                }
                a[rt] = __builtin_bit_cast(bf16x8, u);
            } else {
                const float* Xf = (const float*)Xv;
                const float* p = Xf + (size_t)rA[rt] * F + k0;
                float4 lo = *(const float4*)p;
                float4 hi = *(const float4*)(p + 4);
                if (RELU) {
                    lo.x = fmaxf(lo.x, 0.f); lo.y = fmaxf(lo.y, 0.f);
                    lo.z = fmaxf(lo.z, 0.f); lo.w = fmaxf(lo.w, 0.f);
                    hi.x = fmaxf(hi.x, 0.f); hi.y = fmaxf(hi.y, 0.f);
                    hi.z = fmaxf(hi.z, 0.f); hi.w = fmaxf(hi.w, 0.f);
                }
                ushort8 u;
                u[0] = f2bf(lo.x); u[1] = f2bf(lo.y); u[2] = f2bf(lo.z); u[3] = f2bf(lo.w);
                u[4] = f2bf(hi.x); u[5] = f2bf(hi.y); u[6] = f2bf(hi.z); u[7] = f2bf(hi.w);
                a[rt] = __builtin_bit_cast(bf16x8, u);
            }
        }
#pragma unroll
        for (int ct = 0; ct < 8; ++ct) {
            const int nn = ct * 16 + m15;
            const bf16x8 b = *(const bf16x8*)(WT + nn * WPITCH + k0);  // ds_read_b128
            acc[0][ct] = __builtin_amdgcn_mfma_f32_16x16x32_bf16(a[0], b, acc[0][ct], 0, 0, 0);
            acc[1][ct] = __builtin_amdgcn_mfma_f32_16x16x32_bf16(a[1], b, acc[1][ct], 0, 0, 0);
        }
    }

    // C/D layout: col = lane&15, row = quad*4 + reg (within each 16x16 tile)
#pragma unroll
    for (int rt = 0; rt < 2; ++rt)
#pragma unroll
        for (int reg = 0; reg < 4; ++reg) {
            const int row = rowBase + rt * 16 + quad * 4 + reg;
            if (row < n) {
#pragma unroll
                for (int ct = 0; ct < 8; ++ct)
                    Y[(size_t)row * F + ct * 16 + m15] = f2bf(acc[rt][ct][reg]);
            }
        }
}

// --- counting sort by destination -------------------------------------------

__global__ __launch_bounds__(256) void hist_dst(const int* __restrict__ ei,
                                                int* __restrict__ counts, int E) {
    for (int e = blockIdx.x * 256 + threadIdx.x; e < E; e += gridDim.x * 256)
        atomicAdd(&counts[ei[E + e]], 1);
}

__global__ __launch_bounds__(256) void scan_pass1(const int* __restrict__ counts,
                                                  int* __restrict__ bsum, int n) {
    __shared__ int sh[256];
    const int base = blockIdx.x * 1024 + threadIdx.x * 4;
    int s = 0;
#pragma unroll
    for (int j = 0; j < 4; ++j) {
        const int i = base + j;
        if (i < n) s += counts[i];
    }
    sh[threadIdx.x] = s;
    __syncthreads();
    for (int off = 128; off > 0; off >>= 1) {
        if (threadIdx.x < off) sh[threadIdx.x] += sh[threadIdx.x + off];
        __syncthreads();
    }
    if (threadIdx.x == 0) bsum[blockIdx.x] = sh[0];
}

__global__ __launch_bounds__(256) void scan_pass2(int* __restrict__ bsum, int nb) {
    __shared__ int sh[256];
    int v = (threadIdx.x < nb) ? bsum[threadIdx.x] : 0;
    sh[threadIdx.x] = v;
    __syncthreads();
    for (int off = 1; off < 256; off <<= 1) {
        int t = (threadIdx.x >= off) ? sh[threadIdx.x - off] : 0;
        __syncthreads();
        sh[threadIdx.x] += t;
        __syncthreads();
    }
    if (threadIdx.x < nb) bsum[threadIdx.x] = sh[threadIdx.x] - v;  // exclusive
    if (threadIdx.x == nb) bsum[nb] = sh[nb - 1];                   // total
}

__global__ __launch_bounds__(256) void scan_pass3(const int* __restrict__ counts,
                                                  const int* __restrict__ bsum,
                                                  int* __restrict__ offs,
                                                  int* __restrict__ cursor,
                                                  int n, int nb) {
    __shared__ int sh[256];
    const int base = blockIdx.x * 1024 + threadIdx.x * 4;
    int c[4];
    int s = 0;
#pragma unroll
    for (int j = 0; j < 4; ++j) {
        const int i = base + j;
        c[j] = (i < n) ? counts[i] : 0;
        s += c[j];
    }
    int inc = s;
    sh[threadIdx.x] = inc;
    __syncthreads();
    for (int off = 1; off < 256; off <<= 1) {
        int t = (threadIdx.x >= off) ? sh[threadIdx.x - off] : 0;
        __syncthreads();
        sh[threadIdx.x] += t;
        __syncthreads();
    }
    int run = bsum[blockIdx.x] + sh[threadIdx.x] - inc;
#pragma unroll
    for (int j = 0; j < 4; ++j) {
        const int i = base + j;
        if (i < n) { offs[i] = run; cursor[i] = run; }
        run += c[j];
    }
    if (blockIdx.x == 0 && threadIdx.x == 0) offs[n] = bsum[nb];
}

__global__ __launch_bounds__(256) void bucket_fill(const int* __restrict__ ei,
                                                   const float* __restrict__ ew,
                                                   int* __restrict__ cursor,
                                                   int2* __restrict__ Sedge, int E) {
    const int e = blockIdx.x * 256 + threadIdx.x;
    if (e >= E) return;
    const int dst = ei[E + e];
    const int slot = atomicAdd(&cursor[dst], 1);
    Sedge[slot] = make_int2(ei[e], __float_as_int(ew[e]));
}

// OUT_bf16[v] = sum over incoming edges w_e * XW_bf16[src_e]; 32 lanes per node.
// Each lane covers 4 features (uint2 = 4 bf16), fp32 accumulate, bf16 store.
__global__ __launch_bounds__(256) void gather_agg(const unsigned short* __restrict__ XW,
                                                  const int* __restrict__ offs,
                                                  const int2* __restrict__ Sedge,
                                                  unsigned short* __restrict__ OUT, int n) {
    const int l = threadIdx.x & 31;
    const int v = blockIdx.x * 8 + (threadIdx.x >> 5);
    if (v >= n) return;
    float4 acc = make_float4(0.f, 0.f, 0.f, 0.f);
    const int b = offs[v], e2 = offs[v + 1];
    int p = b;
    for (; p + 4 <= e2; p += 4) {
        const int2 s0 = Sedge[p],     s1 = Sedge[p + 1];
        const int2 s2 = Sedge[p + 2], s3 = Sedge[p + 3];
        const uint2 x0 = ((const uint2*)(XW + (size_t)s0.x * F))[l];
        const uint2 x1 = ((const uint2*)(XW + (size_t)s1.x * F))[l];
        const uint2 x2 = ((const uint2*)(XW + (size_t)s2.x * F))[l];
        const uint2 x3 = ((const uint2*)(XW + (size_t)s3.x * F))[l];
        const float w0 = __int_as_float(s0.y), w1 = __int_as_float(s1.y);
        const float w2 = __int_as_float(s2.y), w3 = __int_as_float(s3.y);
        float a0, a1, a2, a3;
        bf2x(x0.x, a0, a1); bf2x(x0.y, a2, a3);
        acc.x = fmaf(w0, a0, acc.x); acc.y = fmaf(w0, a1, acc.y);
        acc.z = fmaf(w0, a2, acc.z); acc.w = fmaf(w0, a3, acc.w);
        bf2x(x1.x, a0, a1); bf2x(x1.y, a2, a3);
        acc.x = fmaf(w1, a0, acc.x); acc.y = fmaf(w1, a1, acc.y);
        acc.z = fmaf(w1, a2, acc.z); acc.w = fmaf(w1, a3, acc.w);
        bf2x(x2.x, a0, a1); bf2x(x2.y, a2, a3);
        acc.x = fmaf(w2, a0, acc.x); acc.y = fmaf(w2, a1, acc.y);
        acc.z = fmaf(w2, a2, acc.z); acc.w = fmaf(w2, a3, acc.w);
        bf2x(x3.x, a0, a1); bf2x(x3.y, a2, a3);
        acc.x = fmaf(w3, a0, acc.x); acc.y = fmaf(w3, a1, acc.y);
        acc.z = fmaf(w3, a2, acc.z); acc.w = fmaf(w3, a3, acc.w);
    }
    for (; p < e2; ++p) {
        const int2 s = Sedge[p];
        const float w = __int_as_float(s.y);
        const uint2 x = ((const uint2*)(XW + (size_t)s.x * F))[l];
        float a0, a1, a2, a3;
        bf2x(x.x, a0, a1); bf2x(x.y, a2, a3);
        acc.x = fmaf(w, a0, acc.x); acc.y = fmaf(w, a1, acc.y);
        acc.z = fmaf(w, a2, acc.z); acc.w = fmaf(w, a3, acc.w);
    }
    ushort4v o;
    o[0] = f2bf(acc.x); o[1] = f2bf(acc.y); o[2] = f2bf(acc.z); o[3] = f2bf(acc.w);
    *(ushort4v*)(OUT + (size_t)v * F + (size_t)l * 4) = o;
}

// out[p,:] = [Z[a], Z[b]] @ Wlin^T ; one 64-lane wave per pair; Z is bf16.
__global__ __launch_bounds__(256) void pair_lin(const unsigned short* __restrict__ Z,
                                                const int* __restrict__ pos,
                                                const float* __restrict__ Wlin,
                                                float* __restrict__ out, int P) {
    __shared__ float WL[512];
    for (int i = threadIdx.x; i < 512; i += 256) WL[i] = Wlin[i];
    __syncthreads();

    const int lane = threadIdx.x & 63;
    const int p = blockIdx.x * 4 + (threadIdx.x >> 6);
    if (p >= P) return;
    const int a = pos[p];
    const int b = pos[P + p];
    const unsigned int ua = *(const unsigned int*)(Z + (size_t)a * F + lane * 2);
    const unsigned int ub = *(const unsigned int*)(Z + (size_t)b * F + lane * 2);
    float zi0, zi1, zj0, zj1;
    bf2x(ua, zi0, zi1);
    bf2x(ub, zj0, zj1);
    const int k = lane * 2;
    float acc0 = zi0 * WL[k]       + zi1 * WL[k + 1]
               + zj0 * WL[128 + k] + zj1 * WL[128 + k + 1];
    float acc1 = zi0 * WL[256 + k] + zi1 * WL[256 + k + 1]
               + zj0 * WL[384 + k] + zj1 * WL[384 + k + 1];
#pragma unroll
    for (int off = 32; off > 0; off >>= 1) {
        acc0 += __shfl_down(acc0, off, 64);
        acc1 += __shfl_down(acc1, off, 64);
    }
    if (lane == 0) {
        out[(size_t)p * 2 + 0] = acc0;
        out[(size_t)p * 2 + 1] = acc1;
    }
}

extern "C" void kernel_launch(void* const* d_in, const int* in_sizes, int n_in,
                              void* d_out, int out_size, void* d_ws, size_t ws_size,
                              hipStream_t stream) {
    const float* x    = (const float*)d_in[0];
    const int*   ei1  = (const int*)  d_in[1];
    const int*   ei2  = (const int*)  d_in[2];
    const float* ew1  = (const float*)d_in[3];
    const float* ew2  = (const float*)d_in[4];
    const int*   pos  = (const int*)  d_in[5];
    const float* W1   = (const float*)d_in[6];
    const float* W2   = (const float*)d_in[7];
    const float* Wlin = (const float*)d_in[8];
    float* out = (float*)d_out;

    const int N  = in_sizes[0] / F;
    const int E1 = in_sizes[1] / 2;
    const int E2 = in_sizes[2] / 2;
    const int P  = in_sizes[5] / 2;
    const int Emax = E1 > E2 ? E1 : E2;
    const int NB = (N + 1023) / 1024;   // <= 256 required; 98 for N=100k

    // workspace layout (bf16 inter-stage tensors)
    unsigned short* Abf = (unsigned short*)d_ws;   // N x 128 bf16 (GEMM out)
    unsigned short* Bbf = Abf + (size_t)N * F;     // N x 128 bf16 (gather out)
    uintptr_t ip  = (uintptr_t)(Bbf + (size_t)N * F);
    ip = (ip + 15) & ~(uintptr_t)15;
    int*   counts = (int*)ip;                      // N
    int*   offs   = counts + N;                    // N+1
    int*   cursor = offs + N + 1;                  // N
    int*   bsum   = cursor + N;                    // NB+1
    uintptr_t sp  = (uintptr_t)(bsum + NB + 1);
    sp = (sp + 7) & ~(uintptr_t)7;
    int2*  Sedge  = (int2*)sp;                     // Emax (8 B each)

    // ---- layer 1: Abf = x @ W1 ; Bbf = segment_sum over edges1 ----
    gemm128_mfma<0, 0><<<(N + 127) / 128, 256, 0, stream>>>(x, W1, Abf, N);

    hipMemsetAsync(counts, 0, (size_t)N * sizeof(int), stream);
    hist_dst<<<1024, 256, 0, stream>>>(ei1, counts, E1);
    scan_pass1<<<NB, 256, 0, stream>>>(counts, bsum, N);
    scan_pass2<<<1, 256, 0, stream>>>(bsum, NB);
    scan_pass3<<<NB, 256, 0, stream>>>(counts, bsum, offs, cursor, N, NB);
    bucket_fill<<<(E1 + 255) / 256, 256, 0, stream>>>(ei1, ew1, cursor, Sedge, E1);
    gather_agg<<<(N + 7) / 8, 256, 0, stream>>>(Abf, offs, Sedge, Bbf, N);

    // ---- layer 2: Abf = relu(Bbf) @ W2 ; Bbf = segment_sum over edges2 ----
    gemm128_mfma<1, 1><<<(N + 127) / 128, 256, 0, stream>>>(Bbf, W2, Abf, N);

    hipMemsetAsync(counts, 0, (size_t)N * sizeof(int), stream);
    hist_dst<<<1024, 256, 0, stream>>>(ei2, counts, E2);
    scan_pass1<<<NB, 256, 0, stream>>>(counts, bsum, N);
    scan_pass2<<<1, 256, 0, stream>>>(bsum, NB);
    scan_pass3<<<NB, 256, 0, stream>>>(counts, bsum, offs, cursor, N, NB);
    bucket_fill<<<(E2 + 255) / 256, 256, 0, stream>>>(ei2, ew2, cursor, Sedge, E2);
    gather_agg<<<(N + 7) / 8, 256, 0, stream>>>(Abf, offs, Sedge, Bbf, N);

    // ---- head ----
    pair_lin<<<(P + 3) / 4, 256, 0, stream>>>(Bbf, pos, Wlin, out, P);
}

// Round 7
// 399.038 us; speedup vs baseline: 7.7346x; 1.1086x over previous
//
#include <hip/hip_runtime.h>

#define F 128

typedef __bf16 bf16x8 __attribute__((ext_vector_type(8)));
typedef unsigned short ushort8 __attribute__((ext_vector_type(8)));
typedef unsigned short ushort4v __attribute__((ext_vector_type(4)));
typedef float f32x4 __attribute__((ext_vector_type(4)));

// fp32 -> bf16 bits with round-to-nearest-even (inputs finite).
static __device__ __forceinline__ unsigned short f2bf(float f) {
    unsigned int u = __float_as_uint(f);
    u += 0x7fffu + ((u >> 16) & 1u);
    return (unsigned short)(u >> 16);
}
// packed uint (2 bf16) -> 2 floats
static __device__ __forceinline__ void bf2x(unsigned int u, float& lo, float& hi) {
    lo = __uint_as_float(u << 16);
    hi = __uint_as_float(u & 0xffff0000u);
}

#define WPITCH 136  // ushorts per WT row: 128 + 8 pad

// Y_bf16[n,128] = act(X[n,128]) @ W[128,128] via bf16 MFMA, fp32 accumulate.
// INBF: X is bf16 (ushort) rows; else fp32. RELU applied to X.
template <int RELU, int INBF>
__global__ __launch_bounds__(256) void gemm128_mfma(const void* __restrict__ Xv,
                                                    const float* __restrict__ W,
                                                    unsigned short* __restrict__ Y,
                                                    int n) {
    __shared__ __align__(16) unsigned short WT[F * WPITCH];  // WT[col][k], bf16 bits
    for (int idx = threadIdx.x; idx < F * F; idx += 256) {
        const int k = idx >> 7, c = idx & 127;
        WT[c * WPITCH + k] = f2bf(W[idx]);
    }
    __syncthreads();

    const int lane = threadIdx.x & 63;
    const int wv = threadIdx.x >> 6;
    const int m15 = lane & 15;
    const int quad = lane >> 4;
    const int rowBase = blockIdx.x * 128 + wv * 32;

    f32x4 acc[2][8];
#pragma unroll
    for (int rt = 0; rt < 2; ++rt)
#pragma unroll
        for (int ct = 0; ct < 8; ++ct) acc[rt][ct] = (f32x4){0.f, 0.f, 0.f, 0.f};

    int rA[2];
    rA[0] = min(rowBase + m15, n - 1);        // clamped; stores masked below
    rA[1] = min(rowBase + 16 + m15, n - 1);

#pragma unroll
    for (int ks = 0; ks < 4; ++ks) {
        const int k0 = ks * 32 + quad * 8;    // this lane's 8-wide k window
        bf16x8 a[2];
#pragma unroll
        for (int rt = 0; rt < 2; ++rt) {
            if (INBF) {
                const unsigned short* Xb = (const unsigned short*)Xv;
                ushort8 u = *(const ushort8*)(Xb + (size_t)rA[rt] * F + k0);
                if (RELU) {
#pragma unroll
                    for (int j = 0; j < 8; ++j) u[j] = (u[j] & 0x8000u) ? 0 : u[j];
                }
                a[rt] = __builtin_bit_cast(bf16x8, u);
            } else {
                const float* Xf = (const float*)Xv;
                const float* p = Xf + (size_t)rA[rt] * F + k0;
                float4 lo = *(const float4*)p;
                float4 hi = *(const float4*)(p + 4);
                if (RELU) {
                    lo.x = fmaxf(lo.x, 0.f); lo.y = fmaxf(lo.y, 0.f);
                    lo.z = fmaxf(lo.z, 0.f); lo.w = fmaxf(lo.w, 0.f);
                    hi.x = fmaxf(hi.x, 0.f); hi.y = fmaxf(hi.y, 0.f);
                    hi.z = fmaxf(hi.z, 0.f); hi.w = fmaxf(hi.w, 0.f);
                }
                ushort8 u;
                u[0] = f2bf(lo.x); u[1] = f2bf(lo.y); u[2] = f2bf(lo.z); u[3] = f2bf(lo.w);
                u[4] = f2bf(hi.x); u[5] = f2bf(hi.y); u[6] = f2bf(hi.z); u[7] = f2bf(hi.w);
                a[rt] = __builtin_bit_cast(bf16x8, u);
            }
        }
#pragma unroll
        for (int ct = 0; ct < 8; ++ct) {
            const int nn = ct * 16 + m15;
            const bf16x8 b = *(const bf16x8*)(WT + nn * WPITCH + k0);  // ds_read_b128
            acc[0][ct] = __builtin_amdgcn_mfma_f32_16x16x32_bf16(a[0], b, acc[0][ct], 0, 0, 0);
            acc[1][ct] = __builtin_amdgcn_mfma_f32_16x16x32_bf16(a[1], b, acc[1][ct], 0, 0, 0);
        }
    }

    // C/D layout: col = lane&15, row = quad*4 + reg (within each 16x16 tile)
#pragma unroll
    for (int rt = 0; rt < 2; ++rt)
#pragma unroll
        for (int reg = 0; reg < 4; ++reg) {
            const int row = rowBase + rt * 16 + quad * 4 + reg;
            if (row < n) {
#pragma unroll
                for (int ct = 0; ct < 8; ++ct)
                    Y[(size_t)row * F + ct * 16 + m15] = f2bf(acc[rt][ct][reg]);
            }
        }
}

// --- counting sort by destination -------------------------------------------

__global__ __launch_bounds__(256) void hist_dst(const int* __restrict__ ei,
                                                int* __restrict__ counts, int E) {
    for (int e = blockIdx.x * 256 + threadIdx.x; e < E; e += gridDim.x * 256)
        atomicAdd(&counts[ei[E + e]], 1);
}

__global__ __launch_bounds__(256) void scan_pass1(const int* __restrict__ counts,
                                                  int* __restrict__ bsum, int n) {
    __shared__ int sh[256];
    const int base = blockIdx.x * 1024 + threadIdx.x * 4;
    int s = 0;
#pragma unroll
    for (int j = 0; j < 4; ++j) {
        const int i = base + j;
        if (i < n) s += counts[i];
    }
    sh[threadIdx.x] = s;
    __syncthreads();
    for (int off = 128; off > 0; off >>= 1) {
        if (threadIdx.x < off) sh[threadIdx.x] += sh[threadIdx.x + off];
        __syncthreads();
    }
    if (threadIdx.x == 0) bsum[blockIdx.x] = sh[0];
}

__global__ __launch_bounds__(256) void scan_pass2(int* __restrict__ bsum, int nb) {
    __shared__ int sh[256];
    int v = (threadIdx.x < nb) ? bsum[threadIdx.x] : 0;
    sh[threadIdx.x] = v;
    __syncthreads();
    for (int off = 1; off < 256; off <<= 1) {
        int t = (threadIdx.x >= off) ? sh[threadIdx.x - off] : 0;
        __syncthreads();
        sh[threadIdx.x] += t;
        __syncthreads();
    }
    if (threadIdx.x < nb) bsum[threadIdx.x] = sh[threadIdx.x] - v;  // exclusive
    if (threadIdx.x == nb) bsum[nb] = sh[nb - 1];                   // total
}

__global__ __launch_bounds__(256) void scan_pass3(const int* __restrict__ counts,
                                                  const int* __restrict__ bsum,
                                                  int* __restrict__ offs,
                                                  int* __restrict__ cursor,
                                                  int n, int nb) {
    __shared__ int sh[256];
    const int base = blockIdx.x * 1024 + threadIdx.x * 4;
    int c[4];
    int s = 0;
#pragma unroll
    for (int j = 0; j < 4; ++j) {
        const int i = base + j;
        c[j] = (i < n) ? counts[i] : 0;
        s += c[j];
    }
    int inc = s;
    sh[threadIdx.x] = inc;
    __syncthreads();
    for (int off = 1; off < 256; off <<= 1) {
        int t = (threadIdx.x >= off) ? sh[threadIdx.x - off] : 0;
        __syncthreads();
        sh[threadIdx.x] += t;
        __syncthreads();
    }
    int run = bsum[blockIdx.x] + sh[threadIdx.x] - inc;
#pragma unroll
    for (int j = 0; j < 4; ++j) {
        const int i = base + j;
        if (i < n) { offs[i] = run; cursor[i] = run; }
        run += c[j];
    }
    if (blockIdx.x == 0 && threadIdx.x == 0) offs[n] = bsum[nb];
}

__global__ __launch_bounds__(256) void bucket_fill(const int* __restrict__ ei,
                                                   const float* __restrict__ ew,
                                                   int* __restrict__ cursor,
                                                   int2* __restrict__ Sedge, int E) {
    const int e = blockIdx.x * 256 + threadIdx.x;
    if (e >= E) return;
    const int dst = ei[E + e];
    const int slot = atomicAdd(&cursor[dst], 1);
    Sedge[slot] = make_int2(ei[e], __float_as_int(ew[e]));
}

// OUT[v] = sum over incoming edges w_e * XW_bf16[src_e]; 32 lanes per node.
// FUSE_U == 0: write bf16 row to OUT.
// FUSE_U == 1: instead project the fp32 row onto Wlin and write U[v] (float4):
//   U[v] = (dot(Wl0_lo,zv), dot(Wl0_hi,zv), dot(Wl1_lo,zv), dot(Wl1_hi,zv))
template <int FUSE_U>
__global__ __launch_bounds__(256) void gather_agg(const unsigned short* __restrict__ XW,
                                                  const int* __restrict__ offs,
                                                  const int2* __restrict__ Sedge,
                                                  const float* __restrict__ Wlin,
                                                  unsigned short* __restrict__ OUT,
                                                  float4* __restrict__ U, int n) {
    __shared__ float WL[512];
    if (FUSE_U) {
        for (int i = threadIdx.x; i < 512; i += 256) WL[i] = Wlin[i];
        __syncthreads();
    }
    const int l = threadIdx.x & 31;
    const int v = blockIdx.x * 8 + (threadIdx.x >> 5);
    if (v >= n) return;
    float4 acc = make_float4(0.f, 0.f, 0.f, 0.f);
    const int b = offs[v], e2 = offs[v + 1];
    int p = b;
    for (; p + 4 <= e2; p += 4) {
        const int2 s0 = Sedge[p],     s1 = Sedge[p + 1];
        const int2 s2 = Sedge[p + 2], s3 = Sedge[p + 3];
        const uint2 x0 = ((const uint2*)(XW + (size_t)s0.x * F))[l];
        const uint2 x1 = ((const uint2*)(XW + (size_t)s1.x * F))[l];
        const uint2 x2 = ((const uint2*)(XW + (size_t)s2.x * F))[l];
        const uint2 x3 = ((const uint2*)(XW + (size_t)s3.x * F))[l];
        const float w0 = __int_as_float(s0.y), w1 = __int_as_float(s1.y);
        const float w2 = __int_as_float(s2.y), w3 = __int_as_float(s3.y);
        float a0, a1, a2, a3;
        bf2x(x0.x, a0, a1); bf2x(x0.y, a2, a3);
        acc.x = fmaf(w0, a0, acc.x); acc.y = fmaf(w0, a1, acc.y);
        acc.z = fmaf(w0, a2, acc.z); acc.w = fmaf(w0, a3, acc.w);
        bf2x(x1.x, a0, a1); bf2x(x1.y, a2, a3);
        acc.x = fmaf(w1, a0, acc.x); acc.y = fmaf(w1, a1, acc.y);
        acc.z = fmaf(w1, a2, acc.z); acc.w = fmaf(w1, a3, acc.w);
        bf2x(x2.x, a0, a1); bf2x(x2.y, a2, a3);
        acc.x = fmaf(w2, a0, acc.x); acc.y = fmaf(w2, a1, acc.y);
        acc.z = fmaf(w2, a2, acc.z); acc.w = fmaf(w2, a3, acc.w);
        bf2x(x3.x, a0, a1); bf2x(x3.y, a2, a3);
        acc.x = fmaf(w3, a0, acc.x); acc.y = fmaf(w3, a1, acc.y);
        acc.z = fmaf(w3, a2, acc.z); acc.w = fmaf(w3, a3, acc.w);
    }
    for (; p < e2; ++p) {
        const int2 s = Sedge[p];
        const float w = __int_as_float(s.y);
        const uint2 x = ((const uint2*)(XW + (size_t)s.x * F))[l];
        float a0, a1, a2, a3;
        bf2x(x.x, a0, a1); bf2x(x.y, a2, a3);
        acc.x = fmaf(w, a0, acc.x); acc.y = fmaf(w, a1, acc.y);
        acc.z = fmaf(w, a2, acc.z); acc.w = fmaf(w, a3, acc.w);
    }
    if (!FUSE_U) {
        ushort4v o;
        o[0] = f2bf(acc.x); o[1] = f2bf(acc.y); o[2] = f2bf(acc.z); o[3] = f2bf(acc.w);
        *(ushort4v*)(OUT + (size_t)v * F + (size_t)l * 4) = o;
    } else {
        // lane l holds features [4l, 4l+3]; project onto the 4 Wlin half-rows
        const int k = l * 4;
        float s0 = acc.x * WL[k]       + acc.y * WL[k + 1]
                 + acc.z * WL[k + 2]   + acc.w * WL[k + 3];        // Wlin[0, 0:128]
        float s1 = acc.x * WL[128 + k] + acc.y * WL[128 + k + 1]
                 + acc.z * WL[128 + k + 2] + acc.w * WL[128 + k + 3];  // Wlin[0,128:256]
        float s2 = acc.x * WL[256 + k] + acc.y * WL[256 + k + 1]
                 + acc.z * WL[256 + k + 2] + acc.w * WL[256 + k + 3];  // Wlin[1, 0:128]
        float s3 = acc.x * WL[384 + k] + acc.y * WL[384 + k + 1]
                 + acc.z * WL[384 + k + 2] + acc.w * WL[384 + k + 3];  // Wlin[1,128:256]
#pragma unroll
        for (int off = 16; off > 0; off >>= 1) {
            s0 += __shfl_down(s0, off, 32);
            s1 += __shfl_down(s1, off, 32);
            s2 += __shfl_down(s2, off, 32);
            s3 += __shfl_down(s3, off, 32);
        }
        if (l == 0) U[v] = make_float4(s0, s1, s2, s3);
    }
}

// out[p,:] = (U[a].x + U[b].y, U[a].z + U[b].w); one thread per pair.
__global__ __launch_bounds__(256) void pair_combine(const float4* __restrict__ U,
                                                    const int* __restrict__ pos,
                                                    float* __restrict__ out, int P) {
    const int p = blockIdx.x * 256 + threadIdx.x;
    if (p >= P) return;
    const int a = pos[p];
    const int b = pos[P + p];
    const float4 ua = U[a];
    const float4 ub = U[b];
    *(float2*)(out + (size_t)p * 2) = make_float2(ua.x + ub.y, ua.z + ub.w);
}

extern "C" void kernel_launch(void* const* d_in, const int* in_sizes, int n_in,
                              void* d_out, int out_size, void* d_ws, size_t ws_size,
                              hipStream_t stream) {
    const float* x    = (const float*)d_in[0];
    const int*   ei1  = (const int*)  d_in[1];
    const int*   ei2  = (const int*)  d_in[2];
    const float* ew1  = (const float*)d_in[3];
    const float* ew2  = (const float*)d_in[4];
    const int*   pos  = (const int*)  d_in[5];
    const float* W1   = (const float*)d_in[6];
    const float* W2   = (const float*)d_in[7];
    const float* Wlin = (const float*)d_in[8];
    float* out = (float*)d_out;

    const int N  = in_sizes[0] / F;
    const int E1 = in_sizes[1] / 2;
    const int E2 = in_sizes[2] / 2;
    const int P  = in_sizes[5] / 2;
    const int Emax = E1 > E2 ? E1 : E2;
    const int NB = (N + 1023) / 1024;   // <= 256 required; 98 for N=100k

    // workspace layout
    unsigned short* Abf = (unsigned short*)d_ws;   // N x 128 bf16 (GEMM out)
    unsigned short* Bbf = Abf + (size_t)N * F;     // N x 128 bf16 (gather-1 out)
    uintptr_t up  = (uintptr_t)(Bbf + (size_t)N * F);
    up = (up + 15) & ~(uintptr_t)15;
    float4* U     = (float4*)up;                   // N x float4 (node projections)
    int*   counts = (int*)(U + N);                 // N
    int*   offs   = counts + N;                    // N+1
    int*   cursor = offs + N + 1;                  // N
    int*   bsum   = cursor + N;                    // NB+1
    uintptr_t sp  = (uintptr_t)(bsum + NB + 1);
    sp = (sp + 7) & ~(uintptr_t)7;
    int2*  Sedge  = (int2*)sp;                     // Emax (8 B each)

    // ---- layer 1: Abf = x @ W1 ; Bbf = segment_sum over edges1 ----
    gemm128_mfma<0, 0><<<(N + 127) / 128, 256, 0, stream>>>(x, W1, Abf, N);

    hipMemsetAsync(counts, 0, (size_t)N * sizeof(int), stream);
    hist_dst<<<1024, 256, 0, stream>>>(ei1, counts, E1);
    scan_pass1<<<NB, 256, 0, stream>>>(counts, bsum, N);
    scan_pass2<<<1, 256, 0, stream>>>(bsum, NB);
    scan_pass3<<<NB, 256, 0, stream>>>(counts, bsum, offs, cursor, N, NB);
    bucket_fill<<<(E1 + 255) / 256, 256, 0, stream>>>(ei1, ew1, cursor, Sedge, E1);
    gather_agg<0><<<(N + 7) / 8, 256, 0, stream>>>(Abf, offs, Sedge, Wlin, Bbf, U, N);

    // ---- layer 2: Abf = relu(Bbf) @ W2 ; U = Wlin-projected segment_sum over edges2 ----
    gemm128_mfma<1, 1><<<(N + 127) / 128, 256, 0, stream>>>(Bbf, W2, Abf, N);

    hipMemsetAsync(counts, 0, (size_t)N * sizeof(int), stream);
    hist_dst<<<1024, 256, 0, stream>>>(ei2, counts, E2);
    scan_pass1<<<NB, 256, 0, stream>>>(counts, bsum, N);
    scan_pass2<<<1, 256, 0, stream>>>(bsum, NB);
    scan_pass3<<<NB, 256, 0, stream>>>(counts, bsum, offs, cursor, N, NB);
    bucket_fill<<<(E2 + 255) / 256, 256, 0, stream>>>(ei2, ew2, cursor, Sedge, E2);
    gather_agg<1><<<(N + 7) / 8, 256, 0, stream>>>(Abf, offs, Sedge, Wlin, Bbf, U, N);

    // ---- head: out[p] = (U[a].x + U[b].y, U[a].z + U[b].w) ----
    pair_combine<<<(P + 255) / 256, 256, 0, stream>>>(U, pos, out, P);
}